// Round 2
// baseline (1388.634 us; speedup 1.0000x reference)
//
#include <hip/hip_runtime.h>
#include <math.h>

// VQVAE forward — single megakernel, fp32, 64 rows/block.
// LDS: one 16384-float (64 KB) pool, stage-reused. Workspace: hist[1024] + sum_e only.

namespace {

constexpr int kN = 262144;

// Tiled GEMM fragment: 4 rows (tr+16*ri) x NC*16 cols (tc+16*ci), k = nk4*4.
// SA/SW = LDS row strides (floats) for A and W. W is [col][k] (i.e. both row-major
// with k innermost, matching h @ w.T).
template <int SA, int SW, int NC>
__device__ __forceinline__ void gemm_tile(const float* A, const float* W,
                                          int tr, int tc, float (&acc)[4][NC], int nk4) {
#pragma unroll 4
  for (int k4 = 0; k4 < nk4; ++k4) {
    float4 a[4];
#pragma unroll
    for (int ri = 0; ri < 4; ++ri)
      a[ri] = *(const float4*)&A[(tr + 16 * ri) * SA + k4 * 4];
#pragma unroll
    for (int ci = 0; ci < NC; ++ci) {
      float4 w = *(const float4*)&W[(tc + 16 * ci) * SW + k4 * 4];
#pragma unroll
      for (int ri = 0; ri < 4; ++ri) {
        acc[ri][ci] = fmaf(a[ri].x, w.x, acc[ri][ci]);
        acc[ri][ci] = fmaf(a[ri].y, w.y, acc[ri][ci]);
        acc[ri][ci] = fmaf(a[ri].z, w.z, acc[ri][ci]);
        acc[ri][ci] = fmaf(a[ri].w, w.w, acc[ri][ci]);
      }
    }
  }
}

__global__ __launch_bounds__(256) void vqvae_mega(
    const float* __restrict__ x,
    const float* __restrict__ ew1, const float* __restrict__ eb1,
    const float* __restrict__ ew2, const float* __restrict__ eb2,
    const float* __restrict__ ew3, const float* __restrict__ eb3,
    const float* __restrict__ dw1, const float* __restrict__ db1,
    const float* __restrict__ dw2, const float* __restrict__ db2,
    const float* __restrict__ dw3, const float* __restrict__ db3,
    const float* __restrict__ cb,
    float* __restrict__ out, int* __restrict__ hist, float* __restrict__ sum_e) {
  __shared__ __align__(16) float P[16384];  // exactly 64 KB

  const int t = threadIdx.x;
  const int tc = t & 15, tr = t >> 4;
  const long r0 = (long)blockIdx.x * 64;

  // ================= Stage A: enc1 (9->256, relu) fused into enc2 (256->128, relu)
  float* Xs  = P;           // [64][12]
  float* W1c = P + 768;     // [64][12]   (64-wide chunk of enc_w1)
  float* B1c = P + 1536;    // [64]
  float* H1c = P + 1664;    // [64][68]   (64-wide k-chunk of H1)
  float* W2c = P + 6016;    // [128][68]
  float* B2s = P + 14720;   // [128]

  for (int e = t; e < 64 * 9; e += 256) Xs[(e / 9) * 12 + e % 9] = x[r0 * 9 + e];
  if (t < 128) B2s[t] = eb2[t];

  float accA[4][8] = {{0.f}};
  for (int kc = 0; kc < 4; ++kc) {
    __syncthreads();  // protect prev-iter gemm reads (and Xs/B2s staging on kc=0)
    for (int e = t; e < 64 * 9; e += 256)
      W1c[(e / 9) * 12 + e % 9] = ew1[kc * 64 * 9 + e];
    if (t < 64) B1c[t] = eb1[kc * 64 + t];
    {
      const float4* wv = (const float4*)ew2;  // [128][256] -> row stride 64 float4
#pragma unroll
      for (int i = 0; i < 8; ++i) {
        int j = tr + 16 * i;
        *(float4*)&W2c[j * 68 + tc * 4] = wv[j * 64 + kc * 16 + tc];
      }
    }
    __syncthreads();  // W1c/B1c ready
    for (int e = t; e < 64 * 64; e += 256) {
      int r = e >> 6, f = e & 63;
      float4 xa = *(const float4*)&Xs[r * 12];
      float4 xb = *(const float4*)&Xs[r * 12 + 4];
      float x8 = Xs[r * 12 + 8];
      float4 wa = *(const float4*)&W1c[f * 12];
      float4 wb = *(const float4*)&W1c[f * 12 + 4];
      float w8 = W1c[f * 12 + 8];
      float a = B1c[f];
      a = fmaf(xa.x, wa.x, a); a = fmaf(xa.y, wa.y, a);
      a = fmaf(xa.z, wa.z, a); a = fmaf(xa.w, wa.w, a);
      a = fmaf(xb.x, wb.x, a); a = fmaf(xb.y, wb.y, a);
      a = fmaf(xb.z, wb.z, a); a = fmaf(xb.w, wb.w, a);
      a = fmaf(x8, w8, a);
      H1c[r * 68 + f] = fmaxf(a, 0.f);
    }
    __syncthreads();  // H1c/W2c ready
    gemm_tile<68, 68, 8>(H1c, W2c, tr, tc, accA, 16);
  }
  __syncthreads();  // all stage-A reads done; reuse P[0..8448) for H2
  float* H2s = P;   // [64][132]
#pragma unroll
  for (int ri = 0; ri < 4; ++ri) {
    int r = tr + 16 * ri;
#pragma unroll
    for (int ci = 0; ci < 8; ++ci) {
      int j = tc + 16 * ci;
      H2s[r * 132 + j] = fmaxf(accA[ri][ci] + B2s[j], 0.f);
    }
  }

  // ================= Stage B: enc3 (128->64, no relu) -> Z (LDS) + row norms (regs)
  float* W3c = P + 8448;  // [64][68]
  float accZ[4][4] = {{0.f}};
  for (int kc = 0; kc < 2; ++kc) {
    __syncthreads();  // orders H2s writes (kc=0) / prev gemm W3c reads (kc=1)
    {
      const float4* wv = (const float4*)ew3;  // [64][128] -> row stride 32 float4
#pragma unroll
      for (int i = 0; i < 4; ++i) {
        int j = tr + 16 * i;
        *(float4*)&W3c[j * 68 + tc * 4] = wv[j * 32 + kc * 16 + tc];
      }
    }
    __syncthreads();
    gemm_tile<132, 68, 4>(H2s + kc * 64, W3c, tr, tc, accZ, 16);
  }
  float zv[4][4];
  float znr[4];
#pragma unroll
  for (int ri = 0; ri < 4; ++ri) {
    float s = 0.f;
#pragma unroll
    for (int ci = 0; ci < 4; ++ci) {
      float v = accZ[ri][ci] + eb3[tc + 16 * ci];
      zv[ri][ci] = v;
      s = fmaf(v, v, s);
    }
#pragma unroll
    for (int off = 1; off < 16; off <<= 1) s += __shfl_xor(s, off, 16);
    znr[ri] = s;  // ||z_row||^2, all 16 lanes of the row group hold it
  }
  __syncthreads();  // H2s reads done; reuse P[0..4352) for Z
  float* Zs = P;    // [64][68]
#pragma unroll
  for (int ri = 0; ri < 4; ++ri) {
    int r = tr + 16 * ri;
#pragma unroll
    for (int ci = 0; ci < 4; ++ci) Zs[r * 68 + tc + 16 * ci] = zv[ri][ci];
  }

  // ================= Stage C: VQ argmin over 1024 codes (8 chunks of 128)
  float* Cs = P + 4352;     // [128][68]
  float* Cn = P + 13056;    // [128] codebook row norms
  float* RedE = P + 13184;  // [4]
  float bestd[4];
  int besti[4];
#pragma unroll
  for (int ri = 0; ri < 4; ++ri) { bestd[ri] = 3.4e38f; besti[ri] = 0; }

  for (int cc = 0; cc < 8; ++cc) {
    __syncthreads();  // orders Zs writes (cc=0) / prev gemm Cs/Cn reads
    {
      const float4* cv = (const float4*)cb;  // [1024][64] -> row stride 16 float4
#pragma unroll
      for (int i = 0; i < 8; ++i) {
        int j = tr + 16 * i;
        float4 c4 = cv[(cc * 128 + j) * 16 + tc];
        *(float4*)&Cs[j * 68 + tc * 4] = c4;
        float s = c4.x * c4.x;
        s = fmaf(c4.y, c4.y, s); s = fmaf(c4.z, c4.z, s); s = fmaf(c4.w, c4.w, s);
#pragma unroll
        for (int off = 1; off < 16; off <<= 1) s += __shfl_xor(s, off, 16);
        if (tc == 0) Cn[j] = s;
      }
    }
    __syncthreads();
    float accD[4][8] = {{0.f}};
    gemm_tile<68, 68, 8>(Zs, Cs, tr, tc, accD, 16);
#pragma unroll
    for (int ci = 0; ci < 8; ++ci) {
      int j = tc + 16 * ci;
      float cn = Cn[j];
      int gj = cc * 128 + j;
#pragma unroll
      for (int ri = 0; ri < 4; ++ri) {
        float d = znr[ri] - 2.f * accD[ri][ci] + cn;
        if (d < bestd[ri] || (d == bestd[ri] && gj < besti[ri])) {
          bestd[ri] = d; besti[ri] = gj;
        }
      }
    }
  }
  // reduce argmin across the 16 lanes of each row group (tie -> lower index)
#pragma unroll
  for (int ri = 0; ri < 4; ++ri) {
#pragma unroll
    for (int off = 1; off < 16; off <<= 1) {
      float od = __shfl_xor(bestd[ri], off, 16);
      int oi = __shfl_xor(besti[ri], off, 16);
      if (od < bestd[ri] || (od == bestd[ri] && oi < besti[ri])) {
        bestd[ri] = od; besti[ri] = oi;
      }
    }
  }
  if (tc == 0) {
#pragma unroll
    for (int ri = 0; ri < 4; ++ri) atomicAdd(&hist[besti[ri]], 1);
  }
  __syncthreads();  // all Zs/Cs reads done before in-place z_q write
  float es = 0.f;
#pragma unroll
  for (int ri = 0; ri < 4; ++ri) {
    int r = tr + 16 * ri;
    float4 q = *(const float4*)&cb[(size_t)besti[ri] * 64 + tc * 4];
    float4 z4 = *(const float4*)&Zs[r * 68 + tc * 4];
    float dx = q.x - z4.x, dy = q.y - z4.y, dz = q.z - z4.z, dw = q.w - z4.w;
    es = fmaf(dx, dx, es); es = fmaf(dy, dy, es);
    es = fmaf(dz, dz, es); es = fmaf(dw, dw, es);
    float4 a;  // straight-through: z + (q - z), reference rounding
    a.x = z4.x + dx; a.y = z4.y + dy; a.z = z4.z + dz; a.w = z4.w + dw;
    *(float4*)&Zs[r * 68 + tc * 4] = a;
  }
#pragma unroll
  for (int off = 1; off < 64; off <<= 1) es += __shfl_xor(es, off, 64);
  if ((t & 63) == 0) RedE[t >> 6] = es;
  __syncthreads();  // RedE + z_q visible
  if (t == 0) atomicAdd(sum_e, RedE[0] + RedE[1] + RedE[2] + RedE[3]);

  // ================= Stage D: dec1 (64->128, relu)
  float* Wd1 = P + 4352;   // [128][68]
  float* Bd1 = P + 15300;  // [128]
  {
    const float4* wv = (const float4*)dw1;  // [128][64] -> row stride 16 float4
#pragma unroll
    for (int i = 0; i < 8; ++i) {
      int j = tr + 16 * i;
      *(float4*)&Wd1[j * 68 + tc * 4] = wv[j * 16 + tc];
    }
  }
  if (t < 128) Bd1[t] = db1[t];
  __syncthreads();
  float accH[4][8] = {{0.f}};
  gemm_tile<68, 68, 8>(Zs, Wd1, tr, tc, accH, 16);
  __syncthreads();  // Wd1/Zs reads done; reuse for H3 + stage dec_w3
  float* H3s = P + 4352;   // [64][132]
#pragma unroll
  for (int ri = 0; ri < 4; ++ri) {
    int r = tr + 16 * ri;
#pragma unroll
    for (int ci = 0; ci < 8; ++ci) {
      int j = tc + 16 * ci;
      H3s[r * 132 + j] = fmaxf(accH[ri][ci] + Bd1[j], 0.f);
    }
  }
  float* W3d = P + 12800;  // [9][260]
  for (int e = t; e < 9 * 256; e += 256)
    W3d[(e >> 8) * 260 + (e & 255)] = dw3[e];

  // ================= Stage E: dec2 (128->256, relu) fused with dec3 (256->9)
  float* Wd2 = P;          // [64][68]
  float* Bd2 = P + 15200;  // [64]
  float out9[4][9];
#pragma unroll
  for (int ri = 0; ri < 4; ++ri)
#pragma unroll
    for (int o = 0; o < 9; ++o) out9[ri][o] = 0.f;

  for (int jc = 0; jc < 4; ++jc) {
    float accO[4][4] = {{0.f}};
    for (int kc = 0; kc < 2; ++kc) {
      __syncthreads();  // orders H3s/W3d writes (first iter) / prev Wd2+Bd2 reads
      {
        const float4* wv = (const float4*)dw2;  // [256][128] -> row stride 32 float4
#pragma unroll
        for (int i = 0; i < 4; ++i) {
          int j = tr + 16 * i;
          *(float4*)&Wd2[j * 68 + tc * 4] = wv[(size_t)(jc * 64 + j) * 32 + kc * 16 + tc];
        }
      }
      if (kc == 0 && t < 64) Bd2[t] = db2[jc * 64 + t];
      __syncthreads();
      gemm_tile<132, 68, 4>(H3s + kc * 64, Wd2, tr, tc, accO, 16);
    }
    // fold this 64-wide H4 chunk straight into the 9 outputs
#pragma unroll
    for (int ci = 0; ci < 4; ++ci) {
      int j = tc + 16 * ci;
      float b = Bd2[j];
#pragma unroll
      for (int ri = 0; ri < 4; ++ri) {
        float h = fmaxf(accO[ri][ci] + b, 0.f);
#pragma unroll
        for (int o = 0; o < 9; ++o)
          out9[ri][o] = fmaf(h, W3d[o * 260 + jc * 64 + j], out9[ri][o]);
      }
    }
  }
  // reduce out9 across the 16 lanes per row, write x_recon
#pragma unroll
  for (int ri = 0; ri < 4; ++ri) {
#pragma unroll
    for (int o = 0; o < 9; ++o) {
#pragma unroll
      for (int off = 1; off < 16; off <<= 1)
        out9[ri][o] += __shfl_xor(out9[ri][o], off, 16);
    }
  }
#pragma unroll
  for (int ri = 0; ri < 4; ++ri) {
    long r = r0 + tr + 16 * ri;
#pragma unroll
    for (int o = 0; o < 9; ++o)
      if (tc == o) out[r * 9 + o] = out9[ri][o] + db3[o];
  }
}

__global__ void init_kernel(int* hist, float* sum_e) {
  int t = threadIdx.x;
  hist[t] = 0;
  if (t == 0) *sum_e = 0.f;
}

__global__ __launch_bounds__(1024) void finalize_kernel(
    const int* __restrict__ hist, const float* __restrict__ sum_e, float* __restrict__ out2) {
  __shared__ double red[1024];
  int t = threadIdx.x;
  float p = (float)hist[t] * (1.0f / (float)kN);
  red[t] = (double)(p * logf(p + 1e-10f));
  __syncthreads();
  for (int s = 512; s > 0; s >>= 1) {
    if (t < s) red[t] += red[t + s];
    __syncthreads();
  }
  if (t == 0) {
    out2[0] = 1.25f * ((*sum_e) * (1.0f / ((float)kN * 64.0f)));  // q_latent + 0.25*e_latent
    out2[1] = expf((float)(-red[0]));
  }
}

}  // namespace

extern "C" void kernel_launch(void* const* d_in, const int* in_sizes, int n_in,
                              void* d_out, int out_size, void* d_ws, size_t ws_size,
                              hipStream_t stream) {
  const float* x   = (const float*)d_in[0];
  const float* ew1 = (const float*)d_in[1];
  const float* eb1 = (const float*)d_in[2];
  const float* ew2 = (const float*)d_in[3];
  const float* eb2 = (const float*)d_in[4];
  const float* ew3 = (const float*)d_in[5];
  const float* eb3 = (const float*)d_in[6];
  const float* dw1 = (const float*)d_in[7];
  const float* db1 = (const float*)d_in[8];
  const float* dw2 = (const float*)d_in[9];
  const float* db2 = (const float*)d_in[10];
  const float* dw3 = (const float*)d_in[11];
  const float* db3 = (const float*)d_in[12];
  const float* cb  = (const float*)d_in[13];
  float* out = (float*)d_out;

  int* hist = (int*)d_ws;                  // [1024]
  float* sum_e = (float*)(hist + 1024);    // [1]

  init_kernel<<<1, 1024, 0, stream>>>(hist, sum_e);
  vqvae_mega<<<kN / 64, 256, 0, stream>>>(x, ew1, eb1, ew2, eb2, ew3, eb3,
                                          dw1, db1, dw2, db2, dw3, db3, cb,
                                          out, hist, sum_e);
  finalize_kernel<<<1, 1024, 0, stream>>>(hist, sum_e, out + (size_t)kN * 9);
}

// Round 4
// 532.959 us; speedup vs baseline: 2.6055x; 2.6055x over previous
//
#include <hip/hip_runtime.h>
#include <math.h>

// VQVAE forward — full-MFMA megakernel (fp16 split-2 precision for encoder+VQ,
// plain fp16 decoder), 64 rows/block, 4 waves.
// Precision scheme: v = hi + lo (both fp16) carries 22 mantissa bits; GEMMs use
// 3 MFMA products (hi*hi + hi*lo + lo*hi) accumulated in fp32 -> ~2^-24 relative
// error, fp32-class, so argmin matches the reference (R2 fp32 had zero flips at
// absmax 4.9e-4). Decoder is plain fp16 (error ~5e-3 << threshold 1.255).
// Workspace: ~557 KB of pre-split weight planes + cn + hist + sum_e.

namespace {

constexpr int kN = 262144;

typedef _Float16 half8 __attribute__((ext_vector_type(8)));
typedef _Float16 half4v __attribute__((ext_vector_type(4)));
typedef float floatx4 __attribute__((ext_vector_type(4)));

#define MFMA16(a, b, c) __builtin_amdgcn_mfma_f32_16x16x32_f16((a), (b), (c), 0, 0, 0)

// ---- workspace byte offsets
constexpr size_t W1M_O = 0;        // w1 padded [256][32] f16 (k>=9 zero), main
constexpr size_t W1R_O = 16384;    // residual
constexpr size_t E2M_O = 32768;    // ew2 [128][256] f16 main
constexpr size_t E2R_O = 98304;
constexpr size_t E3M_O = 163840;   // ew3 [64][128]
constexpr size_t E3R_O = 180224;
constexpr size_t CBM_O = 196608;   // codebook [1024][64]
constexpr size_t CBR_O = 327680;
constexpr size_t D1P_O = 458752;   // dw1 [128][64] plain f16
constexpr size_t D2P_O = 475136;   // dw2 [256][128] plain f16
constexpr size_t D3P_O = 540672;   // dw3 padded [16][256] plain f16 (n>=9 zero)
constexpr size_t CN_O  = 548864;   // cn [1024] f32
constexpr size_t HIST_O = 552960;  // hist [1024] i32
constexpr size_t SUME_O = 557056;  // sum_e f32

__device__ __forceinline__ void split2(float v, _Float16& hi, _Float16& lo) {
  hi = (_Float16)v;
  lo = (_Float16)(v - (float)hi);
}

// ---- LDS pool offsets (in _Float16 units). Pool = 26624 units = 53248 B.
// Stage A: H1 chunk planes [64][40] + W2 chunk planes [128][40]
constexpr int H1M = 0;      // 2560 units
constexpr int H1R = 2560;
constexpr int W2M = 5120;   // 5120 units
constexpr int W2R = 10240;  // ..15360
// Post-A: H2 planes [64][136]
constexpr int H2M = 0;      // 8704 units
constexpr int H2R = 8704;   // ..17408
// Z planes [64][72]
constexpr int ZM = 17408;   // 4608 units
constexpr int ZR = 22016;   // ..26624
// Stage C: codebook chunk planes [64][72]
constexpr int CBM = 0;      // 4608
constexpr int CBR = 4608;   // ..9216
// z_q main plane overwrites ZM
constexpr int ZQM = 17408;
// Stage D/E
constexpr int H3S = 0;      // [64][136] 8704
constexpr int WD2 = 8704;   // [64][136] 8704 ..17408
constexpr int H4C = 17408;  // [64][72] 4608 ..22016

// =====================================================================
__global__ void prep_kernel(
    const float* __restrict__ ew1, const float* __restrict__ ew2,
    const float* __restrict__ ew3, const float* __restrict__ cb,
    const float* __restrict__ dw1, const float* __restrict__ dw2,
    const float* __restrict__ dw3, char* __restrict__ wsb) {
  _Float16* w1m = (_Float16*)(wsb + W1M_O);
  _Float16* w1r = (_Float16*)(wsb + W1R_O);
  _Float16* e2m = (_Float16*)(wsb + E2M_O);
  _Float16* e2r = (_Float16*)(wsb + E2R_O);
  _Float16* e3m = (_Float16*)(wsb + E3M_O);
  _Float16* e3r = (_Float16*)(wsb + E3R_O);
  _Float16* cbm = (_Float16*)(wsb + CBM_O);
  _Float16* cbr = (_Float16*)(wsb + CBR_O);
  _Float16* d1p = (_Float16*)(wsb + D1P_O);
  _Float16* d2p = (_Float16*)(wsb + D2P_O);
  _Float16* d3p = (_Float16*)(wsb + D3P_O);
  float* cn = (float*)(wsb + CN_O);
  int* hist = (int*)(wsb + HIST_O);
  float* sum_e = (float*)(wsb + SUME_O);

  const int gid = blockIdx.x * 256 + threadIdx.x;
  const int stride = gridDim.x * 256;
  for (int e = gid; e < 256 * 32; e += stride) {
    int n = e >> 5, k = e & 31;
    float v = (k < 9) ? ew1[n * 9 + k] : 0.f;
    split2(v, w1m[e], w1r[e]);
  }
  for (int e = gid; e < 128 * 256; e += stride) split2(ew2[e], e2m[e], e2r[e]);
  for (int e = gid; e < 64 * 128; e += stride) split2(ew3[e], e3m[e], e3r[e]);
  for (int e = gid; e < 1024 * 64; e += stride) split2(cb[e], cbm[e], cbr[e]);
  for (int e = gid; e < 128 * 64; e += stride) d1p[e] = (_Float16)dw1[e];
  for (int e = gid; e < 256 * 128; e += stride) d2p[e] = (_Float16)dw2[e];
  for (int e = gid; e < 16 * 256; e += stride) {
    int n = e >> 8, k = e & 255;
    d3p[e] = (n < 9) ? (_Float16)dw3[n * 256 + k] : (_Float16)0.f;
  }
  for (int i = gid; i < 1024; i += stride) {
    float s = 0.f;
    const float* c = cb + (size_t)i * 64;
#pragma unroll 8
    for (int k = 0; k < 64; ++k) s = fmaf(c[k], c[k], s);
    cn[i] = s;
    hist[i] = 0;
  }
  if (gid == 0) *sum_e = 0.f;
}

// =====================================================================
__global__ __launch_bounds__(256, 3) void vqvae_mega(
    const float* __restrict__ x,
    const float* __restrict__ eb1, const float* __restrict__ eb2,
    const float* __restrict__ eb3, const float* __restrict__ db1,
    const float* __restrict__ db2, const float* __restrict__ db3,
    const float* __restrict__ cb, const char* __restrict__ wsb,
    float* __restrict__ out, int* __restrict__ hist, float* __restrict__ sum_e) {
  __shared__ _Float16 LP[26624];
  __shared__ int Bidx[64];
  __shared__ float RedE[4];

  const int t = threadIdx.x;
  const int lane = t & 63;
  const int w = t >> 6;          // wave id, owns rows 16w..16w+15
  const int m = lane & 15;       // MFMA row/col lane index
  const int q = lane >> 4;       // quad
  const int R0 = blockIdx.x * 64;
  const int wr = 16 * w;         // wave's first local row

  const float* cn_g = (const float*)(wsb + CN_O);

  // ---- enc1 A-fragments from x (registers, K padded 9->32)
  half8 axm = {}, axr = {};
  {
    const int grow = R0 + wr + m;
    if (q == 0) {
#pragma unroll
      for (int j = 0; j < 8; ++j) {
        const float v = x[(size_t)grow * 9 + j];
        const _Float16 hi = (_Float16)v;
        axm[j] = hi;
        axr[j] = (_Float16)(v - (float)hi);
      }
    } else if (q == 1) {
      const float v = x[(size_t)grow * 9 + 8];
      const _Float16 hi = (_Float16)v;
      axm[0] = hi;
      axr[0] = (_Float16)(v - (float)hi);
    }
  }

  // ================= Stage A: enc1 (MFMA, K=32 padded) fused with enc2 (K-chunks of 32)
  floatx4 acc2[8];
#pragma unroll
  for (int nt = 0; nt < 8; ++nt) acc2[nt] = (floatx4){0.f, 0.f, 0.f, 0.f};

  for (int kc = 0; kc < 8; ++kc) {
    __syncthreads();  // prev-iter W2 reads done / first-iter entry
    // stage ew2 chunk planes [128][32] -> LDS [128][40]
    {
      const int p = t >> 7, n = t & 127;
      const char* src = wsb + (p ? E2R_O : E2M_O) + (size_t)n * 512 + kc * 64;
      _Float16* dst = LP + (p ? W2R : W2M) + n * 40;
#pragma unroll
      for (int j = 0; j < 4; ++j)
        *(half8*)(dst + j * 8) = *(const half8*)(src + j * 16);
    }
    // enc1: this kc's 32 H1 features (2 n-tiles), MFMA split-3
#pragma unroll
    for (int ntl = 0; ntl < 2; ++ntl) {
      const int f = kc * 32 + ntl * 16 + m;
      const char* bsrc = wsb + (size_t)f * 64 + q * 16;
      half8 bm = *(const half8*)(bsrc + W1M_O);
      half8 br = *(const half8*)(bsrc + W1R_O);
      floatx4 a = (floatx4){0.f, 0.f, 0.f, 0.f};
      a = MFMA16(axr, bm, a);
      a = MFMA16(axm, br, a);
      a = MFMA16(axm, bm, a);
      const float bias = eb1[f];
#pragma unroll
      for (int reg = 0; reg < 4; ++reg) {
        const float v = fmaxf(a[reg] + bias, 0.f);
        const int row = wr + q * 4 + reg;
        const _Float16 hi = (_Float16)v;
        LP[H1M + row * 40 + ntl * 16 + m] = hi;
        LP[H1R + row * 40 + ntl * 16 + m] = (_Float16)(v - (float)hi);
      }
    }
    __syncthreads();  // W2 chunk + H1 chunk ready
    // enc2 accumulate: one K-step of 32
    const half8 am = *(const half8*)(LP + H1M + (wr + m) * 40 + q * 8);
    const half8 ar = *(const half8*)(LP + H1R + (wr + m) * 40 + q * 8);
#pragma unroll
    for (int nt = 0; nt < 8; ++nt) {
      const half8 bm = *(const half8*)(LP + W2M + (nt * 16 + m) * 40 + q * 8);
      const half8 br = *(const half8*)(LP + W2R + (nt * 16 + m) * 40 + q * 8);
      acc2[nt] = MFMA16(ar, bm, acc2[nt]);
      acc2[nt] = MFMA16(am, br, acc2[nt]);
      acc2[nt] = MFMA16(am, bm, acc2[nt]);
    }
  }
  __syncthreads();  // all W2/H1 reads done; write H2 planes (overlaps W2 region)
#pragma unroll
  for (int nt = 0; nt < 8; ++nt) {
    const float bias = eb2[nt * 16 + m];
#pragma unroll
    for (int reg = 0; reg < 4; ++reg) {
      const float v = fmaxf(acc2[nt][reg] + bias, 0.f);
      const int row = wr + q * 4 + reg;
      const _Float16 hi = (_Float16)v;
      LP[H2M + row * 136 + nt * 16 + m] = hi;
      LP[H2R + row * 136 + nt * 16 + m] = (_Float16)(v - (float)hi);
    }
  }

  // ================= Stage B: enc3 (split-3, B direct from ws; own-wave rows)
  floatx4 acc3[4];
#pragma unroll
  for (int nt = 0; nt < 4; ++nt) acc3[nt] = (floatx4){0.f, 0.f, 0.f, 0.f};
#pragma unroll
  for (int ks = 0; ks < 4; ++ks) {
    const half8 am = *(const half8*)(LP + H2M + (wr + m) * 136 + ks * 32 + q * 8);
    const half8 ar = *(const half8*)(LP + H2R + (wr + m) * 136 + ks * 32 + q * 8);
#pragma unroll
    for (int nt = 0; nt < 4; ++nt) {
      const char* bsrc = wsb + (size_t)(nt * 16 + m) * 256 + ks * 64 + q * 16;
      const half8 bm = *(const half8*)(bsrc + E3M_O);
      const half8 br = *(const half8*)(bsrc + E3R_O);
      acc3[nt] = MFMA16(ar, bm, acc3[nt]);
      acc3[nt] = MFMA16(am, br, acc3[nt]);
      acc3[nt] = MFMA16(am, bm, acc3[nt]);
    }
  }
  // epilogue: z values, row norms (znr per C-row, all 16 lanes), store Z planes
  float znr[4] = {0.f, 0.f, 0.f, 0.f};
  float zv[4][4];
#pragma unroll
  for (int nt = 0; nt < 4; ++nt) {
    const float bias = eb3[nt * 16 + m];
#pragma unroll
    for (int reg = 0; reg < 4; ++reg) {
      const float v = acc3[nt][reg] + bias;
      zv[nt][reg] = v;
      znr[reg] = fmaf(v, v, znr[reg]);
    }
  }
#pragma unroll
  for (int reg = 0; reg < 4; ++reg) {
#pragma unroll
    for (int off = 1; off < 16; off <<= 1)
      znr[reg] += __shfl_xor(znr[reg], off, 16);
  }
#pragma unroll
  for (int nt = 0; nt < 4; ++nt) {
#pragma unroll
    for (int reg = 0; reg < 4; ++reg) {
      const int row = wr + q * 4 + reg;
      const float v = zv[nt][reg];
      const _Float16 hi = (_Float16)v;
      LP[ZM + row * 72 + nt * 16 + m] = hi;
      LP[ZR + row * 72 + nt * 16 + m] = (_Float16)(v - (float)hi);
    }
  }

  // ================= Stage C: VQ argmin over 1024 codes, chunks of 64
  float bestd[4];
  int besti[4];
#pragma unroll
  for (int reg = 0; reg < 4; ++reg) { bestd[reg] = 3.4e38f; besti[reg] = 0; }

  for (int cc = 0; cc < 16; ++cc) {
    __syncthreads();  // prev CB reads done (first iter: other waves' H2 reads done)
    {
      const int p = t >> 7, e = t & 127;
      const int n = e >> 1, hh = e & 1;
      const char* src = wsb + (p ? CBR_O : CBM_O) + (size_t)(cc * 64 + n) * 128 + hh * 64;
      _Float16* dst = LP + (p ? CBR : CBM) + n * 72 + hh * 32;
#pragma unroll
      for (int j = 0; j < 4; ++j)
        *(half8*)(dst + j * 8) = *(const half8*)(src + j * 16);
    }
    __syncthreads();
    floatx4 accd[4];
#pragma unroll
    for (int nt = 0; nt < 4; ++nt) accd[nt] = (floatx4){0.f, 0.f, 0.f, 0.f};
#pragma unroll
    for (int ks = 0; ks < 2; ++ks) {
      const half8 am = *(const half8*)(LP + ZM + (wr + m) * 72 + ks * 32 + q * 8);
      const half8 ar = *(const half8*)(LP + ZR + (wr + m) * 72 + ks * 32 + q * 8);
#pragma unroll
      for (int nt = 0; nt < 4; ++nt) {
        const half8 bm = *(const half8*)(LP + CBM + (nt * 16 + m) * 72 + ks * 32 + q * 8);
        const half8 br = *(const half8*)(LP + CBR + (nt * 16 + m) * 72 + ks * 32 + q * 8);
        accd[nt] = MFMA16(ar, bm, accd[nt]);
        accd[nt] = MFMA16(am, br, accd[nt]);
        accd[nt] = MFMA16(am, bm, accd[nt]);
      }
    }
#pragma unroll
    for (int nt = 0; nt < 4; ++nt) {
      const int code = cc * 64 + nt * 16 + m;
      const float cnv = cn_g[code];
#pragma unroll
      for (int reg = 0; reg < 4; ++reg) {
        const float d = znr[reg] - 2.f * accd[nt][reg] + cnv;
        if (d < bestd[reg]) { bestd[reg] = d; besti[reg] = code; }
      }
    }
  }
  // argmin reduce across the 16 lanes holding this row's codes (tie -> lower idx)
#pragma unroll
  for (int reg = 0; reg < 4; ++reg) {
#pragma unroll
    for (int off = 1; off < 16; off <<= 1) {
      const float od = __shfl_xor(bestd[reg], off, 16);
      const int oi = __shfl_xor(besti[reg], off, 16);
      if (od < bestd[reg] || (od == bestd[reg] && oi < besti[reg])) {
        bestd[reg] = od; besti[reg] = oi;
      }
    }
  }
  if (m == 0) {
#pragma unroll
    for (int reg = 0; reg < 4; ++reg) {
      Bidx[wr + q * 4 + reg] = besti[reg];
      atomicAdd(&hist[besti[reg]], 1);
    }
  }
  __syncthreads();  // Bidx visible; all Z/CB MFMA reads done

  // ---- z_q (straight-through) + e_latent; z reconstructed exactly as hi+lo
  {
    const int tc = t & 15, tr = t >> 4;
    float es = 0.f;
#pragma unroll
    for (int ri = 0; ri < 4; ++ri) {
      const int r = tr + 16 * ri;
      const half4v zm4 = *(const half4v*)(LP + ZM + r * 72 + tc * 4);
      const half4v zr4 = *(const half4v*)(LP + ZR + r * 72 + tc * 4);
      const int bi = Bidx[r];
      const float4 q4 = *(const float4*)&cb[(size_t)bi * 64 + tc * 4];
      const float z0 = (float)zm4[0] + (float)zr4[0];
      const float z1 = (float)zm4[1] + (float)zr4[1];
      const float z2 = (float)zm4[2] + (float)zr4[2];
      const float z3 = (float)zm4[3] + (float)zr4[3];
      const float d0 = q4.x - z0, d1 = q4.y - z1, d2 = q4.z - z2, d3 = q4.w - z3;
      es = fmaf(d0, d0, es); es = fmaf(d1, d1, es);
      es = fmaf(d2, d2, es); es = fmaf(d3, d3, es);
      half4v zq;
      zq[0] = (_Float16)(z0 + d0);
      zq[1] = (_Float16)(z1 + d1);
      zq[2] = (_Float16)(z2 + d2);
      zq[3] = (_Float16)(z3 + d3);
      *(half4v*)(LP + ZQM + r * 72 + tc * 4) = zq;
    }
#pragma unroll
    for (int off = 1; off < 64; off <<= 1) es += __shfl_xor(es, off, 64);
    if (lane == 0) RedE[w] = es;
  }
  __syncthreads();  // z_q planes + RedE visible
  if (t == 0) atomicAdd(sum_e, RedE[0] + RedE[1] + RedE[2] + RedE[3]);

  // ================= Stage D: dec1 (plain fp16), B direct from ws
  floatx4 accd1[8];
#pragma unroll
  for (int nt = 0; nt < 8; ++nt) accd1[nt] = (floatx4){0.f, 0.f, 0.f, 0.f};
#pragma unroll
  for (int ks = 0; ks < 2; ++ks) {
    const half8 am = *(const half8*)(LP + ZQM + (wr + m) * 72 + ks * 32 + q * 8);
#pragma unroll
    for (int nt = 0; nt < 8; ++nt) {
      const half8 b =
          *(const half8*)(wsb + D1P_O + (size_t)(nt * 16 + m) * 128 + ks * 64 + q * 16);
      accd1[nt] = MFMA16(am, b, accd1[nt]);
    }
  }
#pragma unroll
  for (int nt = 0; nt < 8; ++nt) {
    const float bias = db1[nt * 16 + m];
#pragma unroll
    for (int reg = 0; reg < 4; ++reg) {
      const float v = fmaxf(accd1[nt][reg] + bias, 0.f);
      LP[H3S + (wr + q * 4 + reg) * 136 + nt * 16 + m] = (_Float16)v;
    }
  }

  // ================= Stage E: dec2 (plain fp16, n-chunks of 64) fused with dec3
  floatx4 accd3 = (floatx4){0.f, 0.f, 0.f, 0.f};
  for (int jc = 0; jc < 4; ++jc) {
    __syncthreads();  // prev WD2 reads done; (first iter: dec1 ZQ reads done)
    {
      const int n = t >> 2, jj = t & 3;
      const char* src = wsb + D2P_O + (size_t)(jc * 64 + n) * 256 + jj * 64;
      _Float16* dst = LP + WD2 + n * 136 + jj * 32;
#pragma unroll
      for (int j = 0; j < 4; ++j)
        *(half8*)(dst + j * 8) = *(const half8*)(src + j * 16);
    }
    __syncthreads();
    floatx4 accd2[4];
#pragma unroll
    for (int nt = 0; nt < 4; ++nt) accd2[nt] = (floatx4){0.f, 0.f, 0.f, 0.f};
#pragma unroll
    for (int ks = 0; ks < 4; ++ks) {
      const half8 am = *(const half8*)(LP + H3S + (wr + m) * 136 + ks * 32 + q * 8);
#pragma unroll
      for (int nt = 0; nt < 4; ++nt) {
        const half8 b = *(const half8*)(LP + WD2 + (nt * 16 + m) * 136 + ks * 32 + q * 8);
        accd2[nt] = MFMA16(am, b, accd2[nt]);
      }
    }
#pragma unroll
    for (int nt = 0; nt < 4; ++nt) {
      const float bias = db2[jc * 64 + nt * 16 + m];
#pragma unroll
      for (int reg = 0; reg < 4; ++reg) {
        const float v = fmaxf(accd2[nt][reg] + bias, 0.f);
        LP[H4C + (wr + q * 4 + reg) * 72 + nt * 16 + m] = (_Float16)v;
      }
    }
    // dec3 partial over this 64-wide H4 chunk (own-wave rows; in-order LDS)
#pragma unroll
    for (int ks = 0; ks < 2; ++ks) {
      const half8 am = *(const half8*)(LP + H4C + (wr + m) * 72 + ks * 32 + q * 8);
      const half8 b =
          *(const half8*)(wsb + D3P_O + (size_t)m * 512 + jc * 128 + ks * 64 + q * 16);
      accd3 = MFMA16(am, b, accd3);
    }
  }
  // final store: C-layout col m (<9 valid), rows q*4+reg
  if (m < 9) {
    const float bias = db3[m];
#pragma unroll
    for (int reg = 0; reg < 4; ++reg) {
      const size_t r = (size_t)(R0 + wr + q * 4 + reg);
      out[r * 9 + m] = accd3[reg] + bias;
    }
  }
}

// =====================================================================
__global__ __launch_bounds__(1024) void finalize_kernel(
    const int* __restrict__ hist, const float* __restrict__ sum_e,
    float* __restrict__ out2) {
  __shared__ double red[1024];
  const int t = threadIdx.x;
  const float p = (float)hist[t] * (1.0f / (float)kN);
  red[t] = (double)(p * logf(p + 1e-10f));
  __syncthreads();
  for (int s = 512; s > 0; s >>= 1) {
    if (t < s) red[t] += red[t + s];
    __syncthreads();
  }
  if (t == 0) {
    out2[0] = 1.25f * ((*sum_e) * (1.0f / ((float)kN * 64.0f)));
    out2[1] = expf((float)(-red[0]));
  }
}

}  // namespace

extern "C" void kernel_launch(void* const* d_in, const int* in_sizes, int n_in,
                              void* d_out, int out_size, void* d_ws, size_t ws_size,
                              hipStream_t stream) {
  const float* x   = (const float*)d_in[0];
  const float* ew1 = (const float*)d_in[1];
  const float* eb1 = (const float*)d_in[2];
  const float* ew2 = (const float*)d_in[3];
  const float* eb2 = (const float*)d_in[4];
  const float* ew3 = (const float*)d_in[5];
  const float* eb3 = (const float*)d_in[6];
  const float* dw1 = (const float*)d_in[7];
  const float* db1 = (const float*)d_in[8];
  const float* dw2 = (const float*)d_in[9];
  const float* db2 = (const float*)d_in[10];
  const float* dw3 = (const float*)d_in[11];
  const float* db3 = (const float*)d_in[12];
  const float* cb  = (const float*)d_in[13];
  float* out = (float*)d_out;
  char* wsb = (char*)d_ws;

  int* hist = (int*)(wsb + HIST_O);
  float* sum_e = (float*)(wsb + SUME_O);

  prep_kernel<<<128, 256, 0, stream>>>(ew1, ew2, ew3, cb, dw1, dw2, dw3, wsb);
  vqvae_mega<<<kN / 64, 256, 0, stream>>>(x, eb1, eb2, eb3, db1, db2, db3, cb,
                                          wsb, out, hist, sum_e);
  finalize_kernel<<<1, 1024, 0, stream>>>(hist, sum_e, out + (size_t)kN * 9);
}

// Round 5
// 496.904 us; speedup vs baseline: 2.7946x; 1.0726x over previous
//
#include <hip/hip_runtime.h>
#include <math.h>

// VQVAE forward — full-MFMA megakernel, R5: 128 rows/block, 2 row-tiles/wave,
// B-fragment register reuse across row-tiles, activations in registers with
// wave-private LDS scratter/gather (barrier-free), shared LDS staging only for
// the big B matrices (W2 / codebook / dW2). Split-2 fp16 precision on
// encoder+VQ (R4-verified: zero argmin flips), plain fp16 decoder.

namespace {

constexpr int kN = 262144;

typedef _Float16 half8 __attribute__((ext_vector_type(8)));
typedef float floatx4 __attribute__((ext_vector_type(4)));

#define MFMA16(a, b, c) __builtin_amdgcn_mfma_f32_16x16x32_f16((a), (b), (c), 0, 0, 0)

// ---- workspace byte offsets (as R4)
constexpr size_t W1M_O = 0;        // ew1 padded [256][32] f16 (k>=9 zero), main
constexpr size_t W1R_O = 16384;    // residual
constexpr size_t E2M_O = 32768;    // ew2 [128][256] f16 main
constexpr size_t E2R_O = 98304;
constexpr size_t E3M_O = 163840;   // ew3 [64][128]
constexpr size_t E3R_O = 180224;
constexpr size_t CBM_O = 196608;   // codebook [1024][64]
constexpr size_t CBR_O = 327680;
constexpr size_t D1P_O = 458752;   // dw1 [128][64] plain f16
constexpr size_t D2P_O = 475136;   // dw2 [256][128] plain f16
constexpr size_t D3P_O = 540672;   // dw3 padded [16][256] plain f16 (n>=9 zero)
constexpr size_t CN_O  = 548864;   // cn [1024] f32
constexpr size_t HIST_O = 552960;  // hist [1024] i32
constexpr size_t SUME_O = 557056;  // sum_e f32

__device__ __forceinline__ void split2(float v, _Float16& hi, _Float16& lo) {
  hi = (_Float16)v;
  lo = (_Float16)(v - (float)hi);
}

// LDS map (halfs):
//   SHW (shared staging) at 0..10240:
//     W2 chunk  [128][40] x2 planes: M@0, R@5120
//     CB chunk  [64][72]  x2 planes: M@0, R@4608
//     WD2 chunk [64][136] plain:     @0
//   WPS (wave-private scratch): 2560 halfs/wave at 10240 + w*2560
//     H1/H2: [32][40] x2 planes (M@0, R@1280); Z: [16][72] x2 (M@0, R@1152)
//     H3: [32][40] plain; H4: [16][72] plain

// =====================================================================
__global__ void prep_kernel(
    const float* __restrict__ ew1, const float* __restrict__ ew2,
    const float* __restrict__ ew3, const float* __restrict__ cb,
    const float* __restrict__ dw1, const float* __restrict__ dw2,
    const float* __restrict__ dw3, char* __restrict__ wsb) {
  _Float16* w1m = (_Float16*)(wsb + W1M_O);
  _Float16* w1r = (_Float16*)(wsb + W1R_O);
  _Float16* e2m = (_Float16*)(wsb + E2M_O);
  _Float16* e2r = (_Float16*)(wsb + E2R_O);
  _Float16* e3m = (_Float16*)(wsb + E3M_O);
  _Float16* e3r = (_Float16*)(wsb + E3R_O);
  _Float16* cbm = (_Float16*)(wsb + CBM_O);
  _Float16* cbr = (_Float16*)(wsb + CBR_O);
  _Float16* d1p = (_Float16*)(wsb + D1P_O);
  _Float16* d2p = (_Float16*)(wsb + D2P_O);
  _Float16* d3p = (_Float16*)(wsb + D3P_O);
  float* cn = (float*)(wsb + CN_O);
  int* hist = (int*)(wsb + HIST_O);
  float* sum_e = (float*)(wsb + SUME_O);

  const int gid = blockIdx.x * 256 + threadIdx.x;
  const int stride = gridDim.x * 256;
  for (int e = gid; e < 256 * 32; e += stride) {
    int n = e >> 5, k = e & 31;
    float v = (k < 9) ? ew1[n * 9 + k] : 0.f;
    split2(v, w1m[e], w1r[e]);
  }
  for (int e = gid; e < 128 * 256; e += stride) split2(ew2[e], e2m[e], e2r[e]);
  for (int e = gid; e < 64 * 128; e += stride) split2(ew3[e], e3m[e], e3r[e]);
  for (int e = gid; e < 1024 * 64; e += stride) split2(cb[e], cbm[e], cbr[e]);
  for (int e = gid; e < 128 * 64; e += stride) d1p[e] = (_Float16)dw1[e];
  for (int e = gid; e < 256 * 128; e += stride) d2p[e] = (_Float16)dw2[e];
  for (int e = gid; e < 16 * 256; e += stride) {
    int n = e >> 8, k = e & 255;
    d3p[e] = (n < 9) ? (_Float16)dw3[n * 256 + k] : (_Float16)0.f;
  }
  for (int i = gid; i < 1024; i += stride) {
    float s = 0.f;
    const float* c = cb + (size_t)i * 64;
#pragma unroll 8
    for (int k = 0; k < 64; ++k) s = fmaf(c[k], c[k], s);
    cn[i] = s;
    hist[i] = 0;
  }
  if (gid == 0) *sum_e = 0.f;
}

// =====================================================================
__global__ __launch_bounds__(256, 3) void vqvae_mega(
    const float* __restrict__ x,
    const float* __restrict__ eb1, const float* __restrict__ eb2,
    const float* __restrict__ eb3, const float* __restrict__ db1,
    const float* __restrict__ db2, const float* __restrict__ db3,
    const float* __restrict__ cb, const char* __restrict__ wsb,
    float* __restrict__ out, int* __restrict__ hist, float* __restrict__ sum_e) {
  __shared__ _Float16 LP[20480];
  __shared__ int Bidx[128];

  const int t = threadIdx.x;
  const int lane = t & 63;
  const int w = t >> 6;          // wave id; owns rows 32w..32w+31
  const int m = lane & 15;
  const int q = lane >> 4;
  const int R0 = blockIdx.x * 128;
  const int wr0 = 32 * w;
  _Float16* WPS = LP + 10240 + w * 2560;

  const float* cn_g = (const float*)(wsb + CN_O);

  // ---- x fragments (R-layout, K padded 9->32), per row-tile
  half8 axm[2] = {{}, {}}, axr[2] = {{}, {}};
#pragma unroll
  for (int rt = 0; rt < 2; ++rt) {
    const int grow = R0 + wr0 + 16 * rt + m;
    if (q == 0) {
#pragma unroll
      for (int j = 0; j < 8; ++j) {
        const float v = x[(size_t)grow * 9 + j];
        const _Float16 hi = (_Float16)v;
        axm[rt][j] = hi;
        axr[rt][j] = (_Float16)(v - (float)hi);
      }
    } else if (q == 1) {
      const float v = x[(size_t)grow * 9 + 8];
      const _Float16 hi = (_Float16)v;
      axm[rt][0] = hi;
      axr[rt][0] = (_Float16)(v - (float)hi);
    }
  }

  // ================= Stage A: enc1 fused with enc2 (K-chunks of 32)
  floatx4 acc2[8][2];
#pragma unroll
  for (int nt = 0; nt < 8; ++nt)
#pragma unroll
    for (int rt = 0; rt < 2; ++rt) acc2[nt][rt] = (floatx4){0.f, 0.f, 0.f, 0.f};

  for (int kc = 0; kc < 8; ++kc) {
    __syncthreads();  // prev-iter SHW reads done
    {  // stage ew2 chunk [128][32] -> SHW [128][40] x2 planes
      const int p = t >> 7, n = t & 127;
      const char* src = wsb + (p ? E2R_O : E2M_O) + (size_t)n * 512 + kc * 64;
      _Float16* dst = LP + (p ? 5120 : 0) + n * 40;
#pragma unroll
      for (int j = 0; j < 4; ++j)
        *(half8*)(dst + j * 8) = *(const half8*)(src + j * 16);
    }
    // enc1: 32 H1 features this kc, split-3 MFMA, scatter to wave scratch
#pragma unroll
    for (int ntl = 0; ntl < 2; ++ntl) {
      const int f = kc * 32 + ntl * 16 + m;
      const half8 bm = *(const half8*)(wsb + W1M_O + (size_t)f * 64 + q * 16);
      const half8 br = *(const half8*)(wsb + W1R_O + (size_t)f * 64 + q * 16);
      const float bias = eb1[f];
#pragma unroll
      for (int rt = 0; rt < 2; ++rt) {
        floatx4 a = (floatx4){0.f, 0.f, 0.f, 0.f};
        a = MFMA16(axr[rt], bm, a);
        a = MFMA16(axm[rt], br, a);
        a = MFMA16(axm[rt], bm, a);
#pragma unroll
        for (int reg = 0; reg < 4; ++reg) {
          const float v = fmaxf(a[reg] + bias, 0.f);
          const int row = 16 * rt + 4 * q + reg;
          const _Float16 hi = (_Float16)v;
          WPS[row * 40 + ntl * 16 + m] = hi;
          WPS[1280 + row * 40 + ntl * 16 + m] = (_Float16)(v - (float)hi);
        }
      }
    }
    __syncthreads();  // W2 chunk ready
    // enc2: one K-step of 32; B-frags reused across both row-tiles
    half8 am[2], ar[2];
#pragma unroll
    for (int rt = 0; rt < 2; ++rt) {
      am[rt] = *(const half8*)(WPS + (16 * rt + m) * 40 + q * 8);
      ar[rt] = *(const half8*)(WPS + 1280 + (16 * rt + m) * 40 + q * 8);
    }
#pragma unroll
    for (int nt = 0; nt < 8; ++nt) {
      const half8 bm = *(const half8*)(LP + (nt * 16 + m) * 40 + q * 8);
      const half8 br = *(const half8*)(LP + 5120 + (nt * 16 + m) * 40 + q * 8);
#pragma unroll
      for (int rt = 0; rt < 2; ++rt) {
        acc2[nt][rt] = MFMA16(ar[rt], bm, acc2[nt][rt]);
        acc2[nt][rt] = MFMA16(am[rt], br, acc2[nt][rt]);
        acc2[nt][rt] = MFMA16(am[rt], bm, acc2[nt][rt]);
      }
    }
  }

  // ================= Stage B: enc3 (K=128 in 4 steps; H2 via wave scratch)
  floatx4 acc3[4][2];
#pragma unroll
  for (int nt = 0; nt < 4; ++nt)
#pragma unroll
    for (int rt = 0; rt < 2; ++rt) acc3[nt][rt] = (floatx4){0.f, 0.f, 0.f, 0.f};

  for (int ks = 0; ks < 4; ++ks) {
    // scatter H2 feats [32ks..32ks+31] (both rt), split planes
#pragma unroll
    for (int h = 0; h < 2; ++h) {
      const int nt = 2 * ks + h;
      const float bias = eb2[nt * 16 + m];
#pragma unroll
      for (int rt = 0; rt < 2; ++rt) {
#pragma unroll
        for (int reg = 0; reg < 4; ++reg) {
          const float v = fmaxf(acc2[nt][rt][reg] + bias, 0.f);
          const int row = 16 * rt + 4 * q + reg;
          const _Float16 hi = (_Float16)v;
          WPS[row * 40 + h * 16 + m] = hi;
          WPS[1280 + row * 40 + h * 16 + m] = (_Float16)(v - (float)hi);
        }
      }
    }
    half8 am[2], ar[2];
#pragma unroll
    for (int rt = 0; rt < 2; ++rt) {
      am[rt] = *(const half8*)(WPS + (16 * rt + m) * 40 + q * 8);
      ar[rt] = *(const half8*)(WPS + 1280 + (16 * rt + m) * 40 + q * 8);
    }
#pragma unroll
    for (int nt = 0; nt < 4; ++nt) {
      const half8 bm = *(const half8*)(wsb + E3M_O + (size_t)(nt * 16 + m) * 256 + ks * 64 + q * 16);
      const half8 br = *(const half8*)(wsb + E3R_O + (size_t)(nt * 16 + m) * 256 + ks * 64 + q * 16);
#pragma unroll
      for (int rt = 0; rt < 2; ++rt) {
        acc3[nt][rt] = MFMA16(ar[rt], bm, acc3[nt][rt]);
        acc3[nt][rt] = MFMA16(am[rt], br, acc3[nt][rt]);
        acc3[nt][rt] = MFMA16(am[rt], bm, acc3[nt][rt]);
      }
    }
  }

  // ---- Z epilogue: row norms + Z register fragments via wave scratch
  float znr[2][4];
  half8 zfm[2][2], zfr[2][2];
#pragma unroll
  for (int rt = 0; rt < 2; ++rt) {
    float zrow[4][4];
    float s[4] = {0.f, 0.f, 0.f, 0.f};
#pragma unroll
    for (int nt = 0; nt < 4; ++nt) {
      const float bias = eb3[nt * 16 + m];
#pragma unroll
      for (int reg = 0; reg < 4; ++reg) {
        const float v = acc3[nt][rt][reg] + bias;
        zrow[nt][reg] = v;
        s[reg] = fmaf(v, v, s[reg]);
      }
    }
#pragma unroll
    for (int reg = 0; reg < 4; ++reg) {
#pragma unroll
      for (int off = 1; off < 16; off <<= 1) s[reg] += __shfl_xor(s[reg], off, 16);
      znr[rt][reg] = s[reg];
    }
#pragma unroll
    for (int nt = 0; nt < 4; ++nt) {
#pragma unroll
      for (int reg = 0; reg < 4; ++reg) {
        const float v = zrow[nt][reg];
        const int row = 4 * q + reg;
        const _Float16 hi = (_Float16)v;
        WPS[row * 72 + nt * 16 + m] = hi;
        WPS[1152 + row * 72 + nt * 16 + m] = (_Float16)(v - (float)hi);
      }
    }
#pragma unroll
    for (int ks2 = 0; ks2 < 2; ++ks2) {
      zfm[rt][ks2] = *(const half8*)(WPS + m * 72 + ks2 * 32 + q * 8);
      zfr[rt][ks2] = *(const half8*)(WPS + 1152 + m * 72 + ks2 * 32 + q * 8);
    }
  }

  // ================= Stage C: VQ argmin over 1024 codes (16 chunks of 64)
  float bestd[2][4];
  int besti[2][4];
#pragma unroll
  for (int rt = 0; rt < 2; ++rt)
#pragma unroll
    for (int reg = 0; reg < 4; ++reg) { bestd[rt][reg] = 3.4e38f; besti[rt][reg] = 0; }

  for (int cc = 0; cc < 16; ++cc) {
    __syncthreads();  // prev SHW reads done (first iter: stage A W2 reads)
    {  // stage codebook chunk [64][64] -> SHW [64][72] x2 planes
      const int p = t >> 7, e = t & 127;
      const int n = e >> 1, hh = e & 1;
      const char* src = wsb + (p ? CBR_O : CBM_O) + (size_t)(cc * 64 + n) * 128 + hh * 64;
      _Float16* dst = LP + (p ? 4608 : 0) + n * 72 + hh * 32;
#pragma unroll
      for (int j = 0; j < 4; ++j)
        *(half8*)(dst + j * 8) = *(const half8*)(src + j * 16);
    }
    __syncthreads();
    floatx4 accd[4][2];
#pragma unroll
    for (int nt = 0; nt < 4; ++nt)
#pragma unroll
      for (int rt = 0; rt < 2; ++rt) accd[nt][rt] = (floatx4){0.f, 0.f, 0.f, 0.f};
#pragma unroll
    for (int nt = 0; nt < 4; ++nt) {
#pragma unroll
      for (int ks2 = 0; ks2 < 2; ++ks2) {
        const half8 bm = *(const half8*)(LP + (nt * 16 + m) * 72 + ks2 * 32 + q * 8);
        const half8 br = *(const half8*)(LP + 4608 + (nt * 16 + m) * 72 + ks2 * 32 + q * 8);
#pragma unroll
        for (int rt = 0; rt < 2; ++rt) {
          accd[nt][rt] = MFMA16(zfr[rt][ks2], bm, accd[nt][rt]);
          accd[nt][rt] = MFMA16(zfm[rt][ks2], br, accd[nt][rt]);
          accd[nt][rt] = MFMA16(zfm[rt][ks2], bm, accd[nt][rt]);
        }
      }
    }
#pragma unroll
    for (int nt = 0; nt < 4; ++nt) {
      const int code = cc * 64 + nt * 16 + m;
      const float cnv = cn_g[code];
#pragma unroll
      for (int rt = 0; rt < 2; ++rt) {
#pragma unroll
        for (int reg = 0; reg < 4; ++reg) {
          const float d = znr[rt][reg] - 2.f * accd[nt][rt][reg] + cnv;
          if (d < bestd[rt][reg]) { bestd[rt][reg] = d; besti[rt][reg] = code; }
        }
      }
    }
  }
  // argmin reduce across the 16 lanes holding this row's codes (tie -> lower)
#pragma unroll
  for (int rt = 0; rt < 2; ++rt) {
#pragma unroll
    for (int reg = 0; reg < 4; ++reg) {
#pragma unroll
      for (int off = 1; off < 16; off <<= 1) {
        const float od = __shfl_xor(bestd[rt][reg], off, 16);
        const int oi = __shfl_xor(besti[rt][reg], off, 16);
        if (od < bestd[rt][reg] || (od == bestd[rt][reg] && oi < besti[rt][reg])) {
          bestd[rt][reg] = od; besti[rt][reg] = oi;
        }
      }
    }
  }
  if (m == 0) {
#pragma unroll
    for (int rt = 0; rt < 2; ++rt)
#pragma unroll
      for (int reg = 0; reg < 4; ++reg) {
        Bidx[wr0 + 16 * rt + 4 * q + reg] = besti[rt][reg];
        atomicAdd(&hist[besti[rt][reg]], 1);
      }
  }

  // ---- z_q (straight-through, reference rounding) + e_latent; A-frags in regs
  half8 zq[2][2];
  float es = 0.f;
#pragma unroll
  for (int rt = 0; rt < 2; ++rt) {
    const int bi = Bidx[wr0 + 16 * rt + m];  // same-wave write; lgkmcnt ordered
#pragma unroll
    for (int ks2 = 0; ks2 < 2; ++ks2) {
      const float* cp = cb + (size_t)bi * 64 + ks2 * 32 + q * 8;
      const float4 c0 = *(const float4*)cp;
      const float4 c1 = *(const float4*)(cp + 4);
      float cv[8] = {c0.x, c0.y, c0.z, c0.w, c1.x, c1.y, c1.z, c1.w};
#pragma unroll
      for (int j = 0; j < 8; ++j) {
        const float z = (float)zfm[rt][ks2][j] + (float)zfr[rt][ks2][j];
        const float d = cv[j] - z;
        es = fmaf(d, d, es);
        zq[rt][ks2][j] = (_Float16)(z + d);
      }
    }
  }
#pragma unroll
  for (int off = 1; off < 64; off <<= 1) es += __shfl_xor(es, off, 64);
  if (lane == 0) atomicAdd(sum_e, es);

  // ================= Stage D: dec1 (plain fp16, B from global)
  floatx4 accH[8][2];
#pragma unroll
  for (int nt = 0; nt < 8; ++nt)
#pragma unroll
    for (int rt = 0; rt < 2; ++rt) accH[nt][rt] = (floatx4){0.f, 0.f, 0.f, 0.f};
#pragma unroll
  for (int nt = 0; nt < 8; ++nt) {
#pragma unroll
    for (int ks2 = 0; ks2 < 2; ++ks2) {
      const half8 b = *(const half8*)(wsb + D1P_O + (size_t)(nt * 16 + m) * 128 + ks2 * 64 + q * 16);
#pragma unroll
      for (int rt = 0; rt < 2; ++rt) accH[nt][rt] = MFMA16(zq[rt][ks2], b, accH[nt][rt]);
    }
  }
  // H3 register fragments via wave scratch, per 32-feat slice
  half8 h3f[2][4];
  for (int ks = 0; ks < 4; ++ks) {
#pragma unroll
    for (int h = 0; h < 2; ++h) {
      const int nt = 2 * ks + h;
      const float bias = db1[nt * 16 + m];
#pragma unroll
      for (int rt = 0; rt < 2; ++rt)
#pragma unroll
        for (int reg = 0; reg < 4; ++reg) {
          const float v = fmaxf(accH[nt][rt][reg] + bias, 0.f);
          WPS[(16 * rt + 4 * q + reg) * 40 + h * 16 + m] = (_Float16)v;
        }
    }
#pragma unroll
    for (int rt = 0; rt < 2; ++rt)
      h3f[rt][ks] = *(const half8*)(WPS + (16 * rt + m) * 40 + q * 8);
  }

  // ================= Stage E: dec2 (n-chunks of 64, staged) fused with dec3
  floatx4 accO[2] = {(floatx4){0.f, 0.f, 0.f, 0.f}, (floatx4){0.f, 0.f, 0.f, 0.f}};
  for (int jc = 0; jc < 4; ++jc) {
    __syncthreads();  // prev SHW reads done (first iter: VQ CB reads)
    {  // stage dw2 chunk [64][128] -> SHW [64][136] plain
      const int n = t >> 2, jj = t & 3;
      const char* src = wsb + D2P_O + (size_t)(jc * 64 + n) * 256 + jj * 64;
      _Float16* dst = LP + n * 136 + jj * 32;
#pragma unroll
      for (int j = 0; j < 4; ++j)
        *(half8*)(dst + j * 8) = *(const half8*)(src + j * 16);
    }
    __syncthreads();
    floatx4 accD2[4][2];
#pragma unroll
    for (int nt = 0; nt < 4; ++nt)
#pragma unroll
      for (int rt = 0; rt < 2; ++rt) accD2[nt][rt] = (floatx4){0.f, 0.f, 0.f, 0.f};
#pragma unroll
    for (int nt = 0; nt < 4; ++nt) {
#pragma unroll
      for (int ks = 0; ks < 4; ++ks) {
        const half8 b = *(const half8*)(LP + (nt * 16 + m) * 136 + ks * 32 + q * 8);
#pragma unroll
        for (int rt = 0; rt < 2; ++rt) accD2[nt][rt] = MFMA16(h3f[rt][ks], b, accD2[nt][rt]);
      }
    }
    half8 b3[2];
#pragma unroll
    for (int ks2 = 0; ks2 < 2; ++ks2)
      b3[ks2] = *(const half8*)(wsb + D3P_O + (size_t)m * 512 + jc * 128 + ks2 * 64 + q * 16);
#pragma unroll
    for (int rt = 0; rt < 2; ++rt) {
#pragma unroll
      for (int nt = 0; nt < 4; ++nt) {
        const float bias = db2[jc * 64 + nt * 16 + m];
#pragma unroll
        for (int reg = 0; reg < 4; ++reg) {
          const float v = fmaxf(accD2[nt][rt][reg] + bias, 0.f);
          WPS[(4 * q + reg) * 72 + nt * 16 + m] = (_Float16)v;
        }
      }
#pragma unroll
      for (int ks2 = 0; ks2 < 2; ++ks2) {
        const half8 am = *(const half8*)(WPS + m * 72 + ks2 * 32 + q * 8);
        accO[rt] = MFMA16(am, b3[ks2], accO[rt]);
      }
    }
  }
  // final store
  if (m < 9) {
    const float bias = db3[m];
#pragma unroll
    for (int rt = 0; rt < 2; ++rt)
#pragma unroll
      for (int reg = 0; reg < 4; ++reg) {
        const size_t r = (size_t)(R0 + wr0 + 16 * rt + 4 * q + reg);
        out[r * 9 + m] = accO[rt][reg] + bias;
      }
  }
}

// =====================================================================
__global__ __launch_bounds__(1024) void finalize_kernel(
    const int* __restrict__ hist, const float* __restrict__ sum_e,
    float* __restrict__ out2) {
  __shared__ double red[1024];
  const int t = threadIdx.x;
  const float p = (float)hist[t] * (1.0f / (float)kN);
  red[t] = (double)(p * logf(p + 1e-10f));
  __syncthreads();
  for (int s = 512; s > 0; s >>= 1) {
    if (t < s) red[t] += red[t + s];
    __syncthreads();
  }
  if (t == 0) {
    out2[0] = 1.25f * ((*sum_e) * (1.0f / ((float)kN * 64.0f)));
    out2[1] = expf((float)(-red[0]));
  }
}

}  // namespace

extern "C" void kernel_launch(void* const* d_in, const int* in_sizes, int n_in,
                              void* d_out, int out_size, void* d_ws, size_t ws_size,
                              hipStream_t stream) {
  const float* x   = (const float*)d_in[0];
  const float* ew1 = (const float*)d_in[1];
  const float* eb1 = (const float*)d_in[2];
  const float* ew2 = (const float*)d_in[3];
  const float* eb2 = (const float*)d_in[4];
  const float* ew3 = (const float*)d_in[5];
  const float* eb3 = (const float*)d_in[6];
  const float* dw1 = (const float*)d_in[7];
  const float* db1 = (const float*)d_in[8];
  const float* dw2 = (const float*)d_in[9];
  const float* db2 = (const float*)d_in[10];
  const float* dw3 = (const float*)d_in[11];
  const float* db3 = (const float*)d_in[12];
  const float* cb  = (const float*)d_in[13];
  float* out = (float*)d_out;
  char* wsb = (char*)d_ws;

  int* hist = (int*)(wsb + HIST_O);
  float* sum_e = (float*)(wsb + SUME_O);

  prep_kernel<<<128, 256, 0, stream>>>(ew1, ew2, ew3, cb, dw1, dw2, dw3, wsb);
  vqvae_mega<<<kN / 128, 256, 0, stream>>>(x, eb1, eb2, eb3, db1, db2, db3, cb,
                                           wsb, out, hist, sum_e);
  finalize_kernel<<<1, 1024, 0, stream>>>(hist, sum_e, out + (size_t)kN * 9);
}